// Round 9
// baseline (261.181 us; speedup 1.0000x reference)
//
#include <hip/hip_runtime.h>

typedef unsigned long long u64;
typedef unsigned int u32;

#define NTOK 131072
#define DIMS 1024
#define NT   256

// ---------------------------------------------------------------------------
// Kernel A: signatures as 2 bit-planes, TRANSPOSED chunk layout:
//   sigT[kc*2048 + t*8 + j]  (u32), kc 0..3 = plane1 (s>0), kc 4..7 = OR-plane
//   (s>0 | s==0).  u32 word w32 = 2*(c*4+j) (+1 hi half); kc = w32>>3 (+4).
// dist = popc(p1^s1) + popc(p2^s2)  [exact: complements cancel in xor]
//      = 2*popc(p1^s1) when no zeros anywhere (fast path).
// flags[t] = 1 if signature t has any zero element.
// ---------------------------------------------------------------------------
__global__ void sig_kernel(const float* __restrict__ base,
                           const float* __restrict__ deltas,
                           u32* __restrict__ sigT,
                           int* __restrict__ flags)
{
    const int t    = blockIdx.x;    // tile 0..255
    const int lane = threadIdx.x;   // 0..63
    u64 zany = 0;
    #pragma unroll
    for (int c = 0; c < 4; ++c) {
        #pragma unroll
        for (int j = 0; j < 4; ++j) {
            const int d = c * 256 + lane * 4 + j;
            const float b  = base[d];
            const float dl = (t > 0) ? deltas[(size_t)(t - 1) * DIMS + d] : 0.0f;
            const bool use_d = (dl != 0.0f);
            const bool pos  = use_d ? (dl > 0.0f) : (b > 0.0f);
            const bool zero = !use_d && (b == 0.0f);
            const u64 bp = __ballot(pos);
            const u64 bz = __ballot(zero);
            const u64 p2 = bp | bz;
            zany |= bz;
            if (lane == 0) {
                const int w32 = 2 * (c * 4 + j);
                const int kc = w32 >> 3, j8 = w32 & 7;
                sigT[kc * 2048 + t * 8 + j8]           = (u32)bp;
                sigT[kc * 2048 + t * 8 + j8 + 1]       = (u32)(bp >> 32);
                sigT[(kc + 4) * 2048 + t * 8 + j8]     = (u32)p2;
                sigT[(kc + 4) * 2048 + t * 8 + j8 + 1] = (u32)(p2 >> 32);
            }
        }
    }
    if (lane == 0) flags[t] = (zany != 0) ? 1 : 0;
}

// ---------------------------------------------------------------------------
// Kernel B (fused), 512 threads = 8 waves, 64 tokens/block, wave w owns
// tiles [32w, 32w+32).
// Phase 1: 8 waves x 8 tokens ballot-pack x planes into LDS lmask
//   (u32[64][68]); plane1 = x>0 at words 0..31, OR-plane = (x>0)|(x==0) at
//   words 32..63 (so LDS word offset is kc*8 for kc 0..7, matching sigT).
//   Per-wave zero-any flag -> LDS -> block-uniform fast-path decision.
// Phase 2: chunk-major xor/popcount (R8-verified): fast path runs chunks
//   0..3 only and doubles, slow path runs all 8. acc stays ~50 VGPR.
// Epilogue: per-lane argmin, 128B burst store, cross-wave argmin via LDS.
// ---------------------------------------------------------------------------
__global__ __launch_bounds__(512, 4)
void dist_kernel(const float* __restrict__ x,
                 const u32* __restrict__ sigT,
                 const int* __restrict__ flags,
                 float* __restrict__ idx_out,
                 float* __restrict__ dist_out)
{
    __shared__ u32 lmask[64][68];   // 17408 B
    __shared__ int lkey[8][64];     // 2 KB
    __shared__ int zflags[8];

    const int lane = threadIdx.x & 63;
    const int w    = threadIdx.x >> 6;
    const int tok0 = blockIdx.x * 64;

    // sig-zero flag (uniform after __any)
    const int f = flags[lane] | flags[64 + lane] | flags[128 + lane] | flags[192 + lane];
    const bool sig_zero = __any(f != 0);

    // ---- phase 1: ballot-pack 64 token rows into LDS (wave w: 8 tokens) ----
    u64 zany = 0;
    for (int tk = 0; tk < 8; ++tk) {
        const int tok = w * 8 + tk;
        const float4* xr = (const float4*)(x + (size_t)(tok0 + tok) * DIMS);
        #pragma unroll
        for (int c = 0; c < 4; ++c) {
            const float4 v = xr[c * 64 + lane];
            const u64 bp0 = __ballot(v.x > 0.0f); const u64 bz0 = __ballot(v.x == 0.0f);
            const u64 bp1 = __ballot(v.y > 0.0f); const u64 bz1 = __ballot(v.y == 0.0f);
            const u64 bp2 = __ballot(v.z > 0.0f); const u64 bz2 = __ballot(v.z == 0.0f);
            const u64 bp3 = __ballot(v.w > 0.0f); const u64 bz3 = __ballot(v.w == 0.0f);
            zany |= bz0 | bz1 | bz2 | bz3;
            if (lane == 0) {
                u64* row = (u64*)&lmask[tok][0];          // 272B stride, 16B-aligned
                row[c * 4 + 0] = bp0;  row[16 + c * 4 + 0] = bp0 | bz0;
                row[c * 4 + 1] = bp1;  row[16 + c * 4 + 1] = bp1 | bz1;
                row[c * 4 + 2] = bp2;  row[16 + c * 4 + 2] = bp2 | bz2;
                row[c * 4 + 3] = bp3;  row[16 + c * 4 + 3] = bp3 | bz3;
            }
        }
    }
    if (lane == 0) zflags[w] = (zany != 0) ? 1 : 0;
    __syncthreads();

    int zx = 0;
    #pragma unroll
    for (int i = 0; i < 8; ++i) zx |= zflags[i];
    const bool fast = !sig_zero && (zx == 0);

    // ---- phase 2: chunk-major xor/popcount accumulation ----
    const int wbase = __builtin_amdgcn_readfirstlane(w) * 32;  // provably uniform
    u32 acc[32];
    #pragma unroll
    for (int t = 0; t < 32; ++t) acc[t] = 0;

#define CHUNK(kc) { \
        const uint4 ma = *(const uint4*)&lmask[lane][(kc) * 8]; \
        const uint4 mb = *(const uint4*)&lmask[lane][(kc) * 8 + 4]; \
        const u32* __restrict__ sp = sigT + (kc) * 2048 + wbase * 8; \
        _Pragma("unroll") \
        for (int t = 0; t < 32; ++t) { \
            const u32* __restrict__ s8 = sp + t * 8; \
            acc[t] += __popc(ma.x ^ s8[0]) + __popc(ma.y ^ s8[1]) \
                    + __popc(ma.z ^ s8[2]) + __popc(ma.w ^ s8[3]) \
                    + __popc(mb.x ^ s8[4]) + __popc(mb.y ^ s8[5]) \
                    + __popc(mb.z ^ s8[6]) + __popc(mb.w ^ s8[7]); \
        } \
    }

    int shift;
    if (fast) {
        #pragma unroll
        for (int kc = 0; kc < 4; ++kc) CHUNK(kc)
        shift = 1;                 // dist = 2 * acc
    } else {
        #pragma unroll
        for (int kc = 0; kc < 8; ++kc) CHUNK(kc)
        shift = 0;                 // dist = acc(plane1) + acc(OR-plane)
    }
#undef CHUNK

    // ---- epilogue: argmin + burst store (one 128B line per lane) ----
    int bestkey = 0x7fffffff;
    #pragma unroll
    for (int t = 0; t < 32; ++t)
        bestkey = min(bestkey, ((int)(acc[t] << shift) << 8) | (wbase + t));

    float* drow = dist_out + (size_t)(tok0 + lane) * NT + wbase;
    #pragma unroll
    for (int q = 0; q < 8; ++q) {
        float4 dv;
        dv.x = (float)(acc[4 * q + 0] << shift); dv.y = (float)(acc[4 * q + 1] << shift);
        dv.z = (float)(acc[4 * q + 2] << shift); dv.w = (float)(acc[4 * q + 3] << shift);
        *(float4*)(drow + 4 * q) = dv;
    }

    lkey[w][lane] = bestkey;
    __syncthreads();
    if (w == 0) {
        int k = lkey[0][lane];
        #pragma unroll
        for (int i = 1; i < 8; ++i) k = min(k, lkey[i][lane]);
        idx_out[tok0 + lane] = (float)(k & 255);
    }
}

extern "C" void kernel_launch(void* const* d_in, const int* in_sizes, int n_in,
                              void* d_out, int out_size, void* d_ws, size_t ws_size,
                              hipStream_t stream)
{
    const float* x      = (const float*)d_in[0];
    const float* base   = (const float*)d_in[1];
    const float* deltas = (const float*)d_in[2];

    u32* sigT  = (u32*)d_ws;                         // 8*2048*4 = 64 KB
    int* flags = (int*)((char*)d_ws + 65536);        // 256 ints

    float* idx_out  = (float*)d_out;                 // N floats (tile indices)
    float* dist_out = idx_out + NTOK;                // N*T floats

    sig_kernel<<<NT, 64, 0, stream>>>(base, deltas, sigT, flags);
    dist_kernel<<<NTOK / 64, 512, 0, stream>>>(x, sigT, flags, idx_out, dist_out);
}